// Round 1
// baseline (109.273 us; speedup 1.0000x reference)
//
#include <hip/hip_runtime.h>
#include <stdint.h>
#include <math.h>

typedef __bf16 bf16;
typedef __bf16 bf16x8 __attribute__((ext_vector_type(8)));
typedef __bf16 bf16x4 __attribute__((ext_vector_type(4)));
typedef float f32x4 __attribute__((ext_vector_type(4)));

static constexpr int BATCH = 16384;
static constexpr int D_IN  = 1024;
static constexpr int UNITS = 512;
static constexpr int D_OUT = 512;

__device__ __forceinline__ void gll16(const void* g, void* l) {
    __builtin_amdgcn_global_load_lds(
        (const __attribute__((address_space(1))) void*)g,
        (__attribute__((address_space(3))) void*)l,
        16, 0, 0);
}

// ---------------- prep: fp32 -> bf16 elementwise ----------------
__global__ void k_cvt_bf16(const float* __restrict__ in, bf16* __restrict__ out, int n4) {
    int i = blockIdx.x * blockDim.x + threadIdx.x;
    if (i < n4) {
        f32x4 v = ((const f32x4*)in)[i];
        bf16x4 o = { (bf16)v.x, (bf16)v.y, (bf16)v.z, (bf16)v.w };
        ((bf16x4*)out)[i] = o;
    }
}

// ---------------- prep: transpose 512x512 fp32 -> bf16 [N][K] ----------------
__global__ void k_transpose_cvt(const float* __restrict__ in, bf16* __restrict__ out) {
    __shared__ float t[32][33];
    int bx = blockIdx.x, by = blockIdx.y;
    int tx = threadIdx.x, ty = threadIdx.y;
    #pragma unroll
    for (int j = ty; j < 32; j += 8)
        t[j][tx] = in[(size_t)(by * 32 + j) * UNITS + bx * 32 + tx];
    __syncthreads();
    #pragma unroll
    for (int j = ty; j < 32; j += 8)
        out[(size_t)(bx * 32 + j) * UNITS + by * 32 + tx] = (bf16)t[tx][j];
}

// ---------------- fused GEMM ----------------
// C[M,N] = epilogue( A[M,K] @ Bw[N,K]^T + bias )
// EPI 1: out_bf16 = tanh(.)                      (projected)
// EPI 2: a=sigmoid(.); out_f32 = a+(states-a)*exp(-0.1/tau)   (new_states)
// EPI 3: out_f32 = .                             (readout)
template<int K, int EPI, bool AF32>
__global__ __launch_bounds__(256)
void k_gemm(const float* __restrict__ Af, const bf16* __restrict__ Ab,
            const bf16* __restrict__ Bw,
            const float* __restrict__ bias,
            const float* __restrict__ tau,
            const float* __restrict__ states,
            float* __restrict__ outF, bf16* __restrict__ outB,
            int M, int N)
{
    __shared__ bf16 sA[128 * 32];
    __shared__ bf16 sB[128 * 32];

    const int t = threadIdx.x;
    const int ntiles = N >> 7;
    const int mtile = blockIdx.x / ntiles;
    const int ntile = blockIdx.x % ntiles;
    const int m0 = mtile << 7, n0 = ntile << 7;

    const int lane = t & 63;
    const int wave = t >> 6;
    const int wr = (wave >> 1) * 64, wc = (wave & 1) * 64;
    const int l15 = lane & 15;
    const int lk  = (lane >> 4) * 8;

    f32x4 acc[4][4];
    #pragma unroll
    for (int m = 0; m < 4; ++m)
        #pragma unroll
        for (int n = 0; n < 4; ++n)
            acc[m][n] = (f32x4){0.f, 0.f, 0.f, 0.f};

    const int brow = t >> 2, bk8 = (t & 3) * 8;   // gll staging: 64 rows / issue
    const int arow = t >> 1, ak  = (t & 1) * 16;  // fp32 reg-staging: 2 thr / row

    for (int kt = 0; kt < K; kt += 32) {
        if constexpr (AF32) {
            const float* g = Af + (size_t)(m0 + arow) * K + kt + ak;
            f32x4 v0 = ((const f32x4*)g)[0];
            f32x4 v1 = ((const f32x4*)g)[1];
            f32x4 v2 = ((const f32x4*)g)[2];
            f32x4 v3 = ((const f32x4*)g)[3];
            bf16x8 w0 = { (bf16)v0.x, (bf16)v0.y, (bf16)v0.z, (bf16)v0.w,
                          (bf16)v1.x, (bf16)v1.y, (bf16)v1.z, (bf16)v1.w };
            bf16x8 w1 = { (bf16)v2.x, (bf16)v2.y, (bf16)v2.z, (bf16)v2.w,
                          (bf16)v3.x, (bf16)v3.y, (bf16)v3.z, (bf16)v3.w };
            *(bf16x8*)&sA[arow * 32 + ak]     = w0;
            *(bf16x8*)&sA[arow * 32 + ak + 8] = w1;
        } else {
            gll16(Ab + (size_t)(m0 + brow) * K + kt + bk8,      &sA[t * 8]);
            gll16(Ab + (size_t)(m0 + 64 + brow) * K + kt + bk8, &sA[2048 + t * 8]);
        }
        gll16(Bw + (size_t)(n0 + brow) * K + kt + bk8,      &sB[t * 8]);
        gll16(Bw + (size_t)(n0 + 64 + brow) * K + kt + bk8, &sB[2048 + t * 8]);

        __syncthreads();

        bf16x8 afr[4], bfr[4];
        #pragma unroll
        for (int m = 0; m < 4; ++m)
            afr[m] = *(const bf16x8*)&sA[(wr + m * 16 + l15) * 32 + lk];
        #pragma unroll
        for (int n = 0; n < 4; ++n)
            bfr[n] = *(const bf16x8*)&sB[(wc + n * 16 + l15) * 32 + lk];
        #pragma unroll
        for (int m = 0; m < 4; ++m)
            #pragma unroll
            for (int n = 0; n < 4; ++n)
                acc[m][n] = __builtin_amdgcn_mfma_f32_16x16x32_bf16(
                                afr[m], bfr[n], acc[m][n], 0, 0, 0);

        __syncthreads();
    }

    // epilogue: D row = wr + 4*(lane>>4) + r (+16m), col = wc + l15 (+16n)
    const int rbase = m0 + wr + ((lane >> 4) << 2);
    const int cbase = n0 + wc + l15;
    #pragma unroll
    for (int n = 0; n < 4; ++n) {
        const int gc = cbase + n * 16;
        const float bv = bias[gc];
        float dec = 0.f;
        if constexpr (EPI == 2) dec = __expf(-0.1f / tau[gc]);
        #pragma unroll
        for (int m = 0; m < 4; ++m) {
            #pragma unroll
            for (int r = 0; r < 4; ++r) {
                const int gr = rbase + m * 16 + r;
                float v = acc[m][n][r] + bv;
                if constexpr (EPI == 1) {
                    outB[(size_t)gr * N + gc] = (bf16)tanhf(v);
                } else if constexpr (EPI == 2) {
                    float a = 1.0f / (1.0f + __expf(-v));
                    float s = states[(size_t)gr * N + gc];
                    outF[(size_t)gr * N + gc] = a + (s - a) * dec;
                } else {
                    outF[(size_t)gr * N + gc] = v;
                }
            }
        }
    }
}

extern "C" void kernel_launch(void* const* d_in, const int* in_sizes, int n_in,
                              void* d_out, int out_size, void* d_ws, size_t ws_size,
                              hipStream_t stream) {
    const float* x        = (const float*)d_in[0];
    const float* w_in     = (const float*)d_in[1];
    const float* b_in     = (const float*)d_in[2];
    const float* sens_w   = (const float*)d_in[3];
    const float* sens_sig = (const float*)d_in[4];
    const float* tau      = (const float*)d_in[5];
    const float* ro_w     = (const float*)d_in[6];
    const float* ro_b     = (const float*)d_in[7];
    const float* states   = (const float*)d_in[8];

    float* out    = (float*)d_out;                       // [B][D_OUT]  (final)
    float* new_st = out + (size_t)BATCH * D_OUT;         // [B][UNITS]  (final)
    bf16*  proj   = (bf16*)d_out;                        // temp bf16 in first half

    bf16* w_in_bf = (bf16*)d_ws;                         // 512*1024
    bf16* sensT   = w_in_bf + (size_t)UNITS * D_IN;      // 512*512 (transposed)
    bf16* ro_bf   = sensT + (size_t)UNITS * UNITS;       // 512*512

    // weight prep
    k_cvt_bf16<<<(UNITS * D_IN / 4 + 255) / 256, 256, 0, stream>>>(w_in, w_in_bf, UNITS * D_IN / 4);
    k_transpose_cvt<<<dim3(16, 16), dim3(32, 8), 0, stream>>>(sens_w, sensT);
    k_cvt_bf16<<<(UNITS * UNITS / 4 + 255) / 256, 256, 0, stream>>>(ro_w, ro_bf, UNITS * UNITS / 4);

    // GEMM1: projected = tanh(x @ w_in^T + b_in)  -> bf16 (d_out first half, temp)
    k_gemm<1024, 1, true><<<(BATCH / 128) * (UNITS / 128), 256, 0, stream>>>(
        x, nullptr, w_in_bf, b_in, nullptr, nullptr, nullptr, proj, BATCH, UNITS);

    // GEMM2: new_states = sig(proj @ sensT^T + sigma); ODE step  -> fp32 (second half, final)
    k_gemm<512, 2, false><<<(BATCH / 128) * (UNITS / 128), 256, 0, stream>>>(
        nullptr, proj, sensT, sens_sig, tau, states, new_st, nullptr, BATCH, UNITS);

    // GEMM3: output = new_states @ readout^T + ro_b -> fp32 (first half, final)
    k_gemm<512, 3, true><<<(BATCH / 128) * (D_OUT / 128), 256, 0, stream>>>(
        new_st, nullptr, ro_bf, ro_b, nullptr, nullptr, out, nullptr, BATCH, D_OUT);
}

// Round 2
// 99.899 us; speedup vs baseline: 1.0938x; 1.0938x over previous
//
#include <hip/hip_runtime.h>
#include <stdint.h>
#include <math.h>

typedef __bf16 bf16;
typedef __bf16 bf16x8 __attribute__((ext_vector_type(8)));
typedef __bf16 bf16x4 __attribute__((ext_vector_type(4)));
typedef float f32x4 __attribute__((ext_vector_type(4)));

static constexpr int BATCH = 16384;
static constexpr int D_IN  = 1024;
static constexpr int UNITS = 512;
static constexpr int D_OUT = 512;

__device__ __forceinline__ void gll16(const void* g, void* l) {
    __builtin_amdgcn_global_load_lds(
        (const __attribute__((address_space(1))) void*)g,
        (__attribute__((address_space(3))) void*)l,
        16, 0, 0);
}

// ---------------- prep: fp32 -> bf16, 4 elems/thread (weights) ----------------
__global__ void k_cvt_bf16(const float* __restrict__ in, bf16* __restrict__ out, int n4) {
    int i = blockIdx.x * blockDim.x + threadIdx.x;
    if (i < n4) {
        f32x4 v = ((const f32x4*)in)[i];
        bf16x4 o = { (bf16)v.x, (bf16)v.y, (bf16)v.z, (bf16)v.w };
        ((bf16x4*)out)[i] = o;
    }
}

// ---------------- prep: fp32 -> bf16, 8 elems/thread (x, 67 MB) ----------------
__global__ __launch_bounds__(256) void k_cvt8(const float* __restrict__ in, bf16* __restrict__ out, int n8) {
    int i = blockIdx.x * blockDim.x + threadIdx.x;
    if (i < n8) {
        f32x4 a = ((const f32x4*)in)[2 * i];
        f32x4 b = ((const f32x4*)in)[2 * i + 1];
        bf16x8 o = { (bf16)a.x, (bf16)a.y, (bf16)a.z, (bf16)a.w,
                     (bf16)b.x, (bf16)b.y, (bf16)b.z, (bf16)b.w };
        ((bf16x8*)out)[i] = o;
    }
}

// ---------------- prep: transpose 512x512 fp32 -> bf16 [N][K] ----------------
__global__ void k_transpose_cvt(const float* __restrict__ in, bf16* __restrict__ out) {
    __shared__ float t[32][33];
    int bx = blockIdx.x, by = blockIdx.y;
    int tx = threadIdx.x, ty = threadIdx.y;
    #pragma unroll
    for (int j = ty; j < 32; j += 8)
        t[j][tx] = in[(size_t)(by * 32 + j) * UNITS + bx * 32 + tx];
    __syncthreads();
    #pragma unroll
    for (int j = ty; j < 32; j += 8)
        out[(size_t)(bx * 32 + j) * UNITS + by * 32 + tx] = (bf16)t[tx][j];
}

// ---------------- fused GEMM ----------------
// C[M,N] = epilogue( A[M,K] @ Bw[N,K]^T + bias )
// EPI 1: out_bf16 = tanh(.)
// EPI 2: a=sigmoid(.); out_f32 = a+(states-a)*exp(-0.1/tau)
// EPI 3: out_f32 = .
template<int K, int EPI, bool AF32>
__global__ __launch_bounds__(256)
void k_gemm(const float* __restrict__ Af, const bf16* __restrict__ Ab,
            const bf16* __restrict__ Bw,
            const float* __restrict__ bias,
            const float* __restrict__ tau,
            const float* __restrict__ states,
            float* __restrict__ outF, bf16* __restrict__ outB,
            int M, int N)
{
    __shared__ bf16 sA[128 * 32];
    __shared__ bf16 sB[128 * 32];

    const int t = threadIdx.x;
    const int ntiles = N >> 7;
    // XCD-aware swizzle (m157): same-m-strip blocks run co-temporally on one XCD.
    const int nwg = gridDim.x;
    const int d = blockIdx.x;
    const int bid = (d & 7) * (nwg >> 3) + (d >> 3);
    const int mtile = bid / ntiles;
    const int ntile = bid % ntiles;
    const int m0 = mtile << 7, n0 = ntile << 7;

    const int lane = t & 63;
    const int wave = t >> 6;
    const int wr = (wave >> 1) * 64, wc = (wave & 1) * 64;
    const int l15 = lane & 15;
    const int lk  = (lane >> 4) * 8;

    f32x4 acc[4][4];
    #pragma unroll
    for (int m = 0; m < 4; ++m)
        #pragma unroll
        for (int n = 0; n < 4; ++n)
            acc[m][n] = (f32x4){0.f, 0.f, 0.f, 0.f};

    const int brow = t >> 2, bk8 = (t & 3) * 8;   // gll staging: 64 rows / issue
    const int arow = t >> 1, ak  = (t & 1) * 16;  // fp32 reg-staging: 2 thr / row

    for (int kt = 0; kt < K; kt += 32) {
        if constexpr (AF32) {
            const float* g = Af + (size_t)(m0 + arow) * K + kt + ak;
            f32x4 v0 = ((const f32x4*)g)[0];
            f32x4 v1 = ((const f32x4*)g)[1];
            f32x4 v2 = ((const f32x4*)g)[2];
            f32x4 v3 = ((const f32x4*)g)[3];
            bf16x8 w0 = { (bf16)v0.x, (bf16)v0.y, (bf16)v0.z, (bf16)v0.w,
                          (bf16)v1.x, (bf16)v1.y, (bf16)v1.z, (bf16)v1.w };
            bf16x8 w1 = { (bf16)v2.x, (bf16)v2.y, (bf16)v2.z, (bf16)v2.w,
                          (bf16)v3.x, (bf16)v3.y, (bf16)v3.z, (bf16)v3.w };
            *(bf16x8*)&sA[arow * 32 + ak]     = w0;
            *(bf16x8*)&sA[arow * 32 + ak + 8] = w1;
        } else {
            gll16(Ab + (size_t)(m0 + brow) * K + kt + bk8,      &sA[t * 8]);
            gll16(Ab + (size_t)(m0 + 64 + brow) * K + kt + bk8, &sA[2048 + t * 8]);
        }
        gll16(Bw + (size_t)(n0 + brow) * K + kt + bk8,      &sB[t * 8]);
        gll16(Bw + (size_t)(n0 + 64 + brow) * K + kt + bk8, &sB[2048 + t * 8]);

        __syncthreads();

        bf16x8 afr[4], bfr[4];
        #pragma unroll
        for (int m = 0; m < 4; ++m)
            afr[m] = *(const bf16x8*)&sA[(wr + m * 16 + l15) * 32 + lk];
        #pragma unroll
        for (int n = 0; n < 4; ++n)
            bfr[n] = *(const bf16x8*)&sB[(wc + n * 16 + l15) * 32 + lk];
        #pragma unroll
        for (int m = 0; m < 4; ++m)
            #pragma unroll
            for (int n = 0; n < 4; ++n)
                acc[m][n] = __builtin_amdgcn_mfma_f32_16x16x32_bf16(
                                afr[m], bfr[n], acc[m][n], 0, 0, 0);

        __syncthreads();
    }

    // epilogue: D row = wr + 4*(lane>>4) + r (+16m), col = wc + l15 (+16n)
    const int rbase = m0 + wr + ((lane >> 4) << 2);
    const int cbase = n0 + wc + l15;
    #pragma unroll
    for (int n = 0; n < 4; ++n) {
        const int gc = cbase + n * 16;
        const float bv = bias[gc];
        float dec = 0.f;
        if constexpr (EPI == 2) dec = __expf(-0.1f / tau[gc]);
        #pragma unroll
        for (int m = 0; m < 4; ++m) {
            #pragma unroll
            for (int r = 0; r < 4; ++r) {
                const int gr = rbase + m * 16 + r;
                float v = acc[m][n][r] + bv;
                if constexpr (EPI == 1) {
                    // fast tanh: 1 - 2/(1+e^{2v}); saturates correctly at +-inf
                    float tv = 1.0f - 2.0f / (1.0f + __expf(2.0f * v));
                    outB[(size_t)gr * N + gc] = (bf16)tv;
                } else if constexpr (EPI == 2) {
                    float a = 1.0f / (1.0f + __expf(-v));
                    float s = states[(size_t)gr * N + gc];
                    outF[(size_t)gr * N + gc] = a + (s - a) * dec;
                } else {
                    outF[(size_t)gr * N + gc] = v;
                }
            }
        }
    }
}

extern "C" void kernel_launch(void* const* d_in, const int* in_sizes, int n_in,
                              void* d_out, int out_size, void* d_ws, size_t ws_size,
                              hipStream_t stream) {
    const float* x        = (const float*)d_in[0];
    const float* w_in     = (const float*)d_in[1];
    const float* b_in     = (const float*)d_in[2];
    const float* sens_w   = (const float*)d_in[3];
    const float* sens_sig = (const float*)d_in[4];
    const float* tau      = (const float*)d_in[5];
    const float* ro_w     = (const float*)d_in[6];
    const float* ro_b     = (const float*)d_in[7];
    const float* states   = (const float*)d_in[8];

    float* out    = (float*)d_out;                       // [B][D_OUT] (final, GEMM3)
    float* new_st = out + (size_t)BATCH * D_OUT;         // [B][UNITS] (final, GEMM2)
    bf16*  proj   = (bf16*)d_out;                        // temp bf16 in half1 [0,16MB)
    bf16*  x_bf   = (bf16*)new_st;                       // temp bf16 x in half2 (dead before GEMM2 writes)

    bf16* w_in_bf = (bf16*)d_ws;                         // 512*1024
    bf16* sensT   = w_in_bf + (size_t)UNITS * D_IN;      // 512*512 (transposed)
    bf16* ro_bf   = sensT + (size_t)UNITS * UNITS;       // 512*512

    // prep: x -> bf16 (into d_out half2), weights -> bf16 (ws)
    k_cvt8<<<(BATCH * D_IN / 8 + 255) / 256, 256, 0, stream>>>(x, x_bf, BATCH * D_IN / 8);
    k_cvt_bf16<<<(UNITS * D_IN / 4 + 255) / 256, 256, 0, stream>>>(w_in, w_in_bf, UNITS * D_IN / 4);
    k_transpose_cvt<<<dim3(16, 16), dim3(32, 8), 0, stream>>>(sens_w, sensT);
    k_cvt_bf16<<<(UNITS * UNITS / 4 + 255) / 256, 256, 0, stream>>>(ro_w, ro_bf, UNITS * UNITS / 4);

    // GEMM1: proj = tanh(x_bf @ w_in^T + b_in) -> bf16 (half1, temp)
    k_gemm<1024, 1, false><<<(BATCH / 128) * (UNITS / 128), 256, 0, stream>>>(
        nullptr, x_bf, w_in_bf, b_in, nullptr, nullptr, nullptr, proj, BATCH, UNITS);

    // GEMM2: new_st = sig(proj @ sensT^T + sigma); ODE step -> fp32 (half2, final; overwrites dead x_bf)
    k_gemm<512, 2, false><<<(BATCH / 128) * (UNITS / 128), 256, 0, stream>>>(
        nullptr, proj, sensT, sens_sig, tau, states, new_st, nullptr, BATCH, UNITS);

    // GEMM3: out = new_st @ readout^T + ro_b -> fp32 (half1, final; overwrites dead proj)
    k_gemm<512, 3, true><<<(BATCH / 128) * (D_OUT / 128), 256, 0, stream>>>(
        new_st, nullptr, ro_bf, ro_b, nullptr, nullptr, out, nullptr, BATCH, D_OUT);
}

// Round 3
// 88.588 us; speedup vs baseline: 1.2335x; 1.1277x over previous
//
#include <hip/hip_runtime.h>
#include <stdint.h>
#include <math.h>

typedef __bf16 bf16;
typedef __bf16 bf16x8 __attribute__((ext_vector_type(8)));
typedef __bf16 bf16x4 __attribute__((ext_vector_type(4)));
typedef float f32x4 __attribute__((ext_vector_type(4)));

static constexpr int BATCH = 16384;
static constexpr int D_IN  = 1024;
static constexpr int UNITS = 512;
static constexpr int D_OUT = 512;

__device__ __forceinline__ void gll16(const void* g, void* l) {
    __builtin_amdgcn_global_load_lds(
        (const __attribute__((address_space(1))) void*)g,
        (__attribute__((address_space(3))) void*)l,
        16, 0, 0);
}

// ---------------- fused weight prep: one launch ----------------
// blocks [0,512):   w_in   512x1024 fp32 -> bf16
// blocks [512,768): sens_w 512x512 fp32 -> bf16 transposed ([N][K])
// blocks [768,1024): ro_w  512x512 fp32 -> bf16
__global__ __launch_bounds__(256)
void k_prep(const float* __restrict__ w_in, const float* __restrict__ sens_w,
            const float* __restrict__ ro_w,
            bf16* __restrict__ w_in_bf, bf16* __restrict__ sensT, bf16* __restrict__ ro_bf)
{
    __shared__ float tile[32][33];
    const int b = blockIdx.x;
    const int t = threadIdx.x;
    if (b < 512) {
        int i = b * 256 + t;                       // 512*256*4 = 524288 elems
        f32x4 v = ((const f32x4*)w_in)[i];
        bf16x4 o = { (bf16)v.x, (bf16)v.y, (bf16)v.z, (bf16)v.w };
        ((bf16x4*)w_in_bf)[i] = o;
    } else if (b < 768) {
        int bb = b - 512;
        int bx = bb & 15, by = bb >> 4;
        int tx = t & 31, ty = t >> 5;
        #pragma unroll
        for (int j = ty; j < 32; j += 8)
            tile[j][tx] = sens_w[(size_t)(by * 32 + j) * UNITS + bx * 32 + tx];
        __syncthreads();
        #pragma unroll
        for (int j = ty; j < 32; j += 8)
            sensT[(size_t)(bx * 32 + j) * UNITS + by * 32 + tx] = (bf16)tile[tx][j];
    } else {
        int i = (b - 768) * 256 + t;               // 256*256*4 = 262144 elems
        f32x4 v = ((const f32x4*)ro_w)[i];
        bf16x4 o = { (bf16)v.x, (bf16)v.y, (bf16)v.z, (bf16)v.w };
        ((bf16x4*)ro_bf)[i] = o;
    }
}

// ---------------- fused GEMM, 8 waves, 2-phase dbuf ----------------
// C[M,N] = epilogue( A[M,K] @ Bw[N,K]^T + bias )
// EPI 1: out_bf16 = tanh(.)
// EPI 2: a=sigmoid(.); out_f32 = a+(states-a)*exp(-0.1/tau)
// EPI 3: out_f32 = .
template<int K, int EPI, bool AF32>
__global__ __launch_bounds__(512, 4)
void k_gemm(const float* __restrict__ Af, const bf16* __restrict__ Ab,
            const bf16* __restrict__ Bw,
            const float* __restrict__ bias,
            const float* __restrict__ tau,
            const float* __restrict__ states,
            float* __restrict__ outF, bf16* __restrict__ outB,
            int M, int N)
{
    __shared__ bf16 sA[2][128 * 32];
    __shared__ bf16 sB[2][128 * 32];

    const int t = threadIdx.x;
    const int ntiles = N >> 7;
    // XCD-aware swizzle (nwg % 8 == 0)
    const int nwg = gridDim.x;
    const int d = blockIdx.x;
    const int bid = (d & 7) * (nwg >> 3) + (d >> 3);
    const int mtile = bid / ntiles;
    const int ntile = bid % ntiles;
    const int m0 = mtile << 7, n0 = ntile << 7;

    const int lane = t & 63;
    const int wave = t >> 6;            // 0..7  -> 4m x 2n
    const int wr = (wave >> 1) * 32;
    const int wc = (wave & 1) * 64;
    const int l15 = lane & 15;
    const int lk  = (lane >> 4) * 8;

    f32x4 acc[2][4];
    #pragma unroll
    for (int m = 0; m < 2; ++m)
        #pragma unroll
        for (int n = 0; n < 4; ++n)
            acc[m][n] = (f32x4){0.f, 0.f, 0.f, 0.f};

    // staging: 512 threads cover a 128x32 bf16 tile, 8 elems/thread, linear
    const int brow = t >> 2, bk8 = (t & 3) * 8;
    const float* agp = AF32 ? (Af + (size_t)(m0 + brow) * K + bk8) : nullptr;
    const bf16*  abp = AF32 ? nullptr : (Ab + (size_t)(m0 + brow) * K + bk8);
    const bf16*  bbp = Bw + (size_t)(n0 + brow) * K + bk8;

    // ---- prologue: stage tile 0 into buf 0 ----
    if constexpr (AF32) {
        f32x4 v0 = ((const f32x4*)agp)[0];
        f32x4 v1 = ((const f32x4*)agp)[1];
        bf16x8 w = { (bf16)v0.x, (bf16)v0.y, (bf16)v0.z, (bf16)v0.w,
                     (bf16)v1.x, (bf16)v1.y, (bf16)v1.z, (bf16)v1.w };
        *(bf16x8*)&sA[0][t * 8] = w;
    } else {
        gll16(abp, &sA[0][t * 8]);
    }
    gll16(bbp, &sB[0][t * 8]);
    __syncthreads();

    int cur = 0;
    for (int kt = 0; kt < K; kt += 32) {
        const int nxt = kt + 32;
        // ---- issue next tile's loads (prefetch) ----
        f32x4 v0, v1;
        if (nxt < K) {
            if constexpr (AF32) {
                v0 = ((const f32x4*)(agp + nxt))[0];
                v1 = ((const f32x4*)(agp + nxt))[1];
            } else {
                gll16(abp + nxt, &sA[cur ^ 1][t * 8]);
            }
            gll16(bbp + nxt, &sB[cur ^ 1][t * 8]);
        }
        // ---- compute current tile ----
        bf16x8 afr[2], bfr[4];
        #pragma unroll
        for (int m = 0; m < 2; ++m)
            afr[m] = *(const bf16x8*)&sA[cur][(wr + m * 16 + l15) * 32 + lk];
        #pragma unroll
        for (int n = 0; n < 4; ++n)
            bfr[n] = *(const bf16x8*)&sB[cur][(wc + n * 16 + l15) * 32 + lk];
        #pragma unroll
        for (int m = 0; m < 2; ++m)
            #pragma unroll
            for (int n = 0; n < 4; ++n)
                acc[m][n] = __builtin_amdgcn_mfma_f32_16x16x32_bf16(
                                afr[m], bfr[n], acc[m][n], 0, 0, 0);
        // ---- write-late for fp32 A path (T14) ----
        if (nxt < K) {
            if constexpr (AF32) {
                bf16x8 w = { (bf16)v0.x, (bf16)v0.y, (bf16)v0.z, (bf16)v0.w,
                             (bf16)v1.x, (bf16)v1.y, (bf16)v1.z, (bf16)v1.w };
                *(bf16x8*)&sA[cur ^ 1][t * 8] = w;
            }
        }
        __syncthreads();
        cur ^= 1;
    }

    // epilogue: D row = wr + 4*(lane>>4) + r (+16m), col = wc + l15 (+16n)
    const int rbase = m0 + wr + ((lane >> 4) << 2);
    const int cbase = n0 + wc + l15;
    #pragma unroll
    for (int n = 0; n < 4; ++n) {
        const int gc = cbase + n * 16;
        const float bv = bias[gc];
        float dec = 0.f;
        if constexpr (EPI == 2) dec = __expf(-0.1f / tau[gc]);
        #pragma unroll
        for (int m = 0; m < 2; ++m) {
            #pragma unroll
            for (int r = 0; r < 4; ++r) {
                const int gr = rbase + m * 16 + r;
                float v = acc[m][n][r] + bv;
                if constexpr (EPI == 1) {
                    float tv = 1.0f - 2.0f / (1.0f + __expf(2.0f * v));
                    outB[(size_t)gr * N + gc] = (bf16)tv;
                } else if constexpr (EPI == 2) {
                    float a = 1.0f / (1.0f + __expf(-v));
                    float s = states[(size_t)gr * N + gc];
                    outF[(size_t)gr * N + gc] = a + (s - a) * dec;
                } else {
                    outF[(size_t)gr * N + gc] = v;
                }
            }
        }
    }
}

extern "C" void kernel_launch(void* const* d_in, const int* in_sizes, int n_in,
                              void* d_out, int out_size, void* d_ws, size_t ws_size,
                              hipStream_t stream) {
    const float* x        = (const float*)d_in[0];
    const float* w_in     = (const float*)d_in[1];
    const float* b_in     = (const float*)d_in[2];
    const float* sens_w   = (const float*)d_in[3];
    const float* sens_sig = (const float*)d_in[4];
    const float* tau      = (const float*)d_in[5];
    const float* ro_w     = (const float*)d_in[6];
    const float* ro_b     = (const float*)d_in[7];
    const float* states   = (const float*)d_in[8];

    float* out    = (float*)d_out;                       // [B][D_OUT] (final, GEMM3)
    float* new_st = out + (size_t)BATCH * D_OUT;         // [B][UNITS] (final, GEMM2)
    bf16*  proj   = (bf16*)d_out;                        // temp bf16 in half1

    bf16* w_in_bf = (bf16*)d_ws;                         // 512*1024
    bf16* sensT   = w_in_bf + (size_t)UNITS * D_IN;      // 512*512 (transposed)
    bf16* ro_bf   = sensT + (size_t)UNITS * UNITS;       // 512*512

    // fused weight prep (single launch)
    k_prep<<<1024, 256, 0, stream>>>(w_in, sens_w, ro_w, w_in_bf, sensT, ro_bf);

    // GEMM1: proj = tanh(x @ w_in^T + b_in) -> bf16 (half1, temp); fp32 A in-kernel cvt
    k_gemm<1024, 1, true><<<(BATCH / 128) * (UNITS / 128), 512, 0, stream>>>(
        x, nullptr, w_in_bf, b_in, nullptr, nullptr, nullptr, proj, BATCH, UNITS);

    // GEMM2: new_st = sig(proj @ sensT^T + sigma); ODE step -> fp32 (half2, final)
    k_gemm<512, 2, false><<<(BATCH / 128) * (UNITS / 128), 512, 0, stream>>>(
        nullptr, proj, sensT, sens_sig, tau, states, new_st, nullptr, BATCH, UNITS);

    // GEMM3: out = new_st @ readout^T + ro_b -> fp32 (half1, final; overwrites dead proj)
    k_gemm<512, 3, true><<<(BATCH / 128) * (D_OUT / 128), 512, 0, stream>>>(
        new_st, nullptr, ro_bf, ro_b, nullptr, nullptr, out, nullptr, BATCH, D_OUT);
}